// Round 8
// baseline (404.318 us; speedup 1.0000x reference)
//
#include <hip/hip_runtime.h>
#include <hip/hip_bf16.h>

#define SQ   2048
#define DIMM 1536
#define QS   4608          // fused qkv row stride
#define NH   12
#define DH   128
#define NQB  16
#define NKB  32
#define KSEL 7

typedef unsigned short u16;
typedef __bf16 bf16x8 __attribute__((ext_vector_type(8)));
typedef _Float16 f16x8 __attribute__((ext_vector_type(8)));
typedef short  s16x8  __attribute__((ext_vector_type(8)));
typedef unsigned short u16x4 __attribute__((ext_vector_type(4)));
typedef float  f32x4  __attribute__((ext_vector_type(4)));
typedef float  f32x2  __attribute__((ext_vector_type(2)));

__device__ __forceinline__ float bf2f(u16 u) {
  unsigned int x = ((unsigned int)u) << 16;
  return __builtin_bit_cast(float, x);
}
__device__ __forceinline__ u16 f2bf(float f) {
  unsigned int x = __builtin_bit_cast(unsigned int, f);
  x += 0x7fffu + ((x >> 16) & 1u);
  return (u16)(x >> 16);
}

typedef __attribute__((address_space(3))) void lds_vt;
typedef const __attribute__((address_space(1))) void g_vt;
__device__ __forceinline__ void dma16(const void* g, void* l) {
  __builtin_amdgcn_global_load_lds((g_vt*)g, (lds_vt*)l, 16, 0, 0);
}

// ---------------- prep: hs f32 -> hi/lo bf16 [r][k] -----------------------
__global__ __launch_bounds__(256) void prep_hs(const float* __restrict__ hs,
                                               u16* __restrict__ hh,
                                               u16* __restrict__ hl) {
  size_t i = ((size_t)blockIdx.x * 256 + threadIdx.x) * 8;
  f32x4 a = *(const f32x4*)&hs[i];
  f32x4 b = *(const f32x4*)&hs[i + 4];
  s16x8 h, l;
  #pragma unroll
  for (int j = 0; j < 4; j++) {
    u16 hj = f2bf(a[j]); h[j] = (short)hj; l[j] = (short)f2bf(a[j] - bf2f(hj));
    u16 hk = f2bf(b[j]); h[4 + j] = (short)hk; l[4 + j] = (short)f2bf(b[j] - bf2f(hk));
  }
  *(s16x8*)&hh[i] = h;
  *(s16x8*)&hl[i] = l;
}

// ---------------- prep: W f32 [k][n] -> WT bf16 hi/lo (wi 0-2) / f16 (wi 3)
__global__ __launch_bounds__(256) void prep_w(const float* __restrict__ W0,
                                              const float* __restrict__ W1,
                                              const float* __restrict__ W2,
                                              const float* __restrict__ W3,
                                              u16* __restrict__ WTh,
                                              u16* __restrict__ WTl) {
  __shared__ float tile[64][65];
  int wi = blockIdx.z;
  const float* W = (wi == 0) ? W0 : (wi == 1) ? W1 : (wi == 2) ? W2 : W3;
  int x = threadIdx.x & 63, y = threadIdx.x >> 6;   // 64 x 4
  int k0 = blockIdx.y * 64, n0 = blockIdx.x * 64;
  #pragma unroll
  for (int i = 0; i < 16; i++) {
    int k = y + i * 4;
    tile[k][x] = W[(size_t)(k0 + k) * DIMM + n0 + x];
  }
  __syncthreads();
  size_t obase = (size_t)wi * DIMM * DIMM;
  #pragma unroll
  for (int i = 0; i < 16; i++) {
    int n = y + i * 4;
    float v = tile[x][n];                 // = W[k0+x][n0+n]
    size_t oi = obase + (size_t)(n0 + n) * DIMM + k0 + x;
    if (wi == 3) {
      WTh[oi] = __builtin_bit_cast(u16, (_Float16)v);   // O-proj: f16 single
    } else {
      u16 h = f2bf(v);
      WTh[oi] = h;
      WTl[oi] = f2bf(v - bf2f(h));
    }
  }
}

// ---------------- fused QKV GEMM: C[2048][4608] = hs @ {Wq,Wk,Wv} + bias --
// Split-bf16 3-pass MFMA (~f24) for Q/K; single-pass for V (smooth path).
// 128x128 tile, BK=128 (12 K-iters -> half the barrier drains of BK=64).
// XOR-swizzled LDS: LDS[row][chunk] = global[row][(c&8)|((c^(row&7))&7)]
// (16B chunks; rows are 256B = 2 bank wraps, swizzle period 8 chunks).
__global__ __launch_bounds__(256) void gemm3_k(const u16* __restrict__ Ahp,
                                               const u16* __restrict__ Alp,
                                               const u16* __restrict__ WTh,
                                               const u16* __restrict__ WTl,
                                               const float* __restrict__ bq,
                                               const float* __restrict__ bk,
                                               const float* __restrict__ bv,
                                               float* __restrict__ C) {
  __shared__ u16 As[2][128][128];   // [hi/lo][row][k swizzled]  64 KB
  __shared__ u16 Bs[2][128][128];   //                           64 KB
  const int tid = threadIdx.x;
  const int w = tid >> 6, lane = tid & 63, quad = lane >> 4, l16 = lane & 15;
  const int wr = w >> 1, wc = w & 1;
  const int m_base = blockIdx.y * 128;
  const int nt = blockIdx.x;                 // 0..35
  const int wi = nt / 12;
  const int n_in = (nt % 12) * 128;
  const u16* Bh0 = WTh + ((size_t)wi * DIMM + n_in) * DIMM;
  const u16* Bl0 = WTl + ((size_t)wi * DIMM + n_in) * DIMM;
  const float* bias = (wi == 0) ? bq : (wi == 1) ? bk : bv;
  const bool split = (wi != 2);              // V = single-pass

  const int srow = lane >> 4;                // 0..3  (4 rows per dma16)
  const int c16 = lane & 15;                 // chunk 0..15
  const int rx = l16 & 7;

  f32x4 zero4 = {0.f, 0.f, 0.f, 0.f};
  f32x4 acc[4][4];
  #pragma unroll
  for (int i = 0; i < 4; i++)
    #pragma unroll
    for (int j = 0; j < 4; j++) acc[i][j] = zero4;

  for (int k0 = 0; k0 < DIMM; k0 += 128) {
    #pragma unroll
    for (int c = 0; c < 8; c++) {
      int r0 = w * 32 + c * 4;
      int row = r0 + srow;
      int scol = ((c16 & 8) | ((c16 ^ (row & 7)) & 7)) * 8;
      dma16(&Ahp[(size_t)(m_base + row) * DIMM + k0 + scol], &As[0][r0][0]);
      dma16(&Bh0[(size_t)row * DIMM + k0 + scol], &Bs[0][r0][0]);
      if (split) {
        dma16(&Alp[(size_t)(m_base + row) * DIMM + k0 + scol], &As[1][r0][0]);
        dma16(&Bl0[(size_t)row * DIMM + k0 + scol], &Bs[1][r0][0]);
      }
    }
    __syncthreads();
    #pragma unroll
    for (int kk = 0; kk < 4; kk++) {
      const int kkq = kk * 4 + quad;
      const int coff = ((kkq & 8) | ((kkq ^ rx) & 7)) * 8;
      bf16x8 afh[4], afl[4], bfh[4], bfl[4];
      #pragma unroll
      for (int i = 0; i < 4; i++)
        afh[i] = __builtin_bit_cast(bf16x8,
                 *(const s16x8*)&As[0][wr * 64 + i * 16 + l16][coff]);
      #pragma unroll
      for (int j = 0; j < 4; j++)
        bfh[j] = __builtin_bit_cast(bf16x8,
                 *(const s16x8*)&Bs[0][wc * 64 + j * 16 + l16][coff]);
      if (split) {
        #pragma unroll
        for (int i = 0; i < 4; i++)
          afl[i] = __builtin_bit_cast(bf16x8,
                   *(const s16x8*)&As[1][wr * 64 + i * 16 + l16][coff]);
        #pragma unroll
        for (int j = 0; j < 4; j++)
          bfl[j] = __builtin_bit_cast(bf16x8,
                   *(const s16x8*)&Bs[1][wc * 64 + j * 16 + l16][coff]);
      }
      #pragma unroll
      for (int i = 0; i < 4; i++)
        #pragma unroll
        for (int j = 0; j < 4; j++) {
          acc[i][j] = __builtin_amdgcn_mfma_f32_16x16x32_bf16(afh[i], bfh[j], acc[i][j], 0, 0, 0);
          if (split) {
            acc[i][j] = __builtin_amdgcn_mfma_f32_16x16x32_bf16(afh[i], bfl[j], acc[i][j], 0, 0, 0);
            acc[i][j] = __builtin_amdgcn_mfma_f32_16x16x32_bf16(afl[i], bfh[j], acc[i][j], 0, 0, 0);
          }
        }
    }
    __syncthreads();
  }
  #pragma unroll
  for (int i = 0; i < 4; i++)
    #pragma unroll
    for (int j = 0; j < 4; j++) {
      int tc = wc * 64 + j * 16 + l16;
      float bv2 = bias[n_in + tc];
      #pragma unroll
      for (int rg = 0; rg < 4; rg++) {
        int r = m_base + wr * 64 + i * 16 + quad * 4 + rg;
        C[(size_t)r * QS + nt * 128 + tc] = acc[i][j][rg] + bv2;
      }
    }
}

// ---------------- O GEMM: C = of @ Wo + bo.  Single-pass f16, 64x128, BK=64
// 24 KB LDS -> multiple blocks/CU cover barrier drains.
__global__ __launch_bounds__(256) void gemm_o(const u16* __restrict__ Ap,
                                              const u16* __restrict__ Bp,
                                              const float* __restrict__ bias,
                                              float* __restrict__ C) {
  __shared__ u16 As[64][64];
  __shared__ u16 Bs[128][64];
  const int tid = threadIdx.x;
  const int w = tid >> 6, lane = tid & 63, quad = lane >> 4, l16 = lane & 15;
  const int wr = w >> 1, wc = w & 1;
  const int m_base = blockIdx.y * 64, n_base = blockIdx.x * 128;
  const int srow = lane >> 3;
  const int skc = (((lane & 7) ^ srow) * 8);
  const int rx = (l16 & 7);

  f32x4 zero4 = {0.f, 0.f, 0.f, 0.f};
  f32x4 acc[2][4];
  #pragma unroll
  for (int i = 0; i < 2; i++)
    #pragma unroll
    for (int j = 0; j < 4; j++) acc[i][j] = zero4;

  for (int k0 = 0; k0 < DIMM; k0 += 64) {
    #pragma unroll
    for (int c = 0; c < 2; c++) {
      int r0 = w * 16 + c * 8;
      int row = r0 + srow;
      dma16(&Ap[(size_t)(m_base + row) * DIMM + k0 + skc], &As[r0][0]);
    }
    #pragma unroll
    for (int c = 0; c < 4; c++) {
      int r0 = w * 32 + c * 8;
      int row = r0 + srow;
      dma16(&Bp[(size_t)(n_base + row) * DIMM + k0 + skc], &Bs[r0][0]);
    }
    __syncthreads();
    #pragma unroll
    for (int kk = 0; kk < 2; kk++) {
      const int coff = ((kk * 4 + quad) ^ rx) * 8;
      f16x8 af[2], bf[4];
      #pragma unroll
      for (int i = 0; i < 2; i++)
        af[i] = __builtin_bit_cast(f16x8,
                *(const s16x8*)&As[wr * 32 + i * 16 + l16][coff]);
      #pragma unroll
      for (int j = 0; j < 4; j++)
        bf[j] = __builtin_bit_cast(f16x8,
                *(const s16x8*)&Bs[wc * 64 + j * 16 + l16][coff]);
      #pragma unroll
      for (int i = 0; i < 2; i++)
        #pragma unroll
        for (int j = 0; j < 4; j++)
          acc[i][j] = __builtin_amdgcn_mfma_f32_16x16x32_f16(af[i], bf[j], acc[i][j], 0, 0, 0);
    }
    __syncthreads();
  }
  #pragma unroll
  for (int i = 0; i < 2; i++)
    #pragma unroll
    for (int j = 0; j < 4; j++) {
      int c = n_base + wc * 64 + j * 16 + l16;
      float bv2 = bias[c];
      #pragma unroll
      for (int rg = 0; rg < 4; rg++) {
        int r = m_base + wr * 32 + i * 16 + quad * 4 + rg;
        C[(size_t)r * DIMM + c] = acc[i][j][rg] + bv2;
      }
    }
}

// ---------------- RMSNorm + RoPE (on fused qkv buffer) --------------------
__global__ __launch_bounds__(256) void norm_rope_k(float* __restrict__ qkv,
                                                   const float* __restrict__ gq,
                                                   const float* __restrict__ gk,
                                                   const float* __restrict__ fc,
                                                   const float* __restrict__ fs) {
  int s = blockIdx.x;
  float* row = qkv + (size_t)s * QS + (blockIdx.y == 0 ? 0 : DIMM);
  const float* g = (blockIdx.y == 0) ? gq : gk;
  int t = threadIdx.x;
  float ss = 0.f;
  #pragma unroll
  for (int i = 0; i < 6; i++) {
    float v = row[t + i * 256];
    ss += v * v;
  }
  #pragma unroll
  for (int m = 1; m < 64; m <<= 1) ss += __shfl_xor(ss, m, 64);
  __shared__ float wsum[4];
  if ((t & 63) == 0) wsum[t >> 6] = ss;
  __syncthreads();
  float tot = wsum[0] + wsum[1] + wsum[2] + wsum[3];
  float sc = rsqrtf(tot / 1536.0f + 1e-6f);
  #pragma unroll
  for (int i = 0; i < 3; i++) {
    int p = t + i * 256;
    int h = p >> 6, ip = p & 63;
    int base = h * 128 + 2 * ip;
    float x1 = row[base] * sc * g[base];
    float x2 = row[base + 1] * sc * g[base + 1];
    float c = fc[(size_t)s * 128 + 2 * ip];
    float sn = fs[(size_t)s * 128 + 2 * ip + 1];
    row[base]     = x1 * c - x2 * sn;
    row[base + 1] = x1 * sn + x2 * c;
  }
}

// ---------------- block means -------------------------------------------
__global__ __launch_bounds__(128) void means_k(const float* __restrict__ qf,
                                               const float* __restrict__ kf,
                                               float* __restrict__ qb,
                                               float* __restrict__ kb) {
  int h = blockIdx.y, t = threadIdx.x;
  if (blockIdx.x < NQB) {
    int qi = blockIdx.x;
    float a = 0.f;
    for (int r = 0; r < 128; r++) a += qf[(size_t)(qi * 128 + r) * QS + h * DH + t];
    qb[(h * NQB + qi) * DH + t] = a * (1.0f / 128.0f);
  } else {
    int ki = blockIdx.x - NQB;
    float a = 0.f;
    for (int r = 0; r < 64; r++) a += kf[(size_t)(ki * 64 + r) * QS + h * DH + t];
    kb[(h * NKB + ki) * DH + t] = a * (1.0f / 64.0f);
  }
}

// ---------------- block scores + top-7 selection -------------------------
__global__ __launch_bounds__(64) void topk_k(const float* __restrict__ qb,
                                             const float* __restrict__ kb,
                                             int* __restrict__ sel) {
  int h = blockIdx.y, qi = blockIdx.x, t = threadIdx.x;
  __shared__ float scs[NKB];
  if (t < NKB) {
    float a = 0.f;
    for (int d = 0; d < DH; d++)
      a += qb[(h * NQB + qi) * DH + d] * kb[(h * NKB + t) * DH + d];
    scs[t] = a;
  }
  __syncthreads();
  if (t == 0) {
    unsigned int used = 0;
    for (int it = 0; it < KSEL; it++) {
      float best = -3.4e38f; int bi = 0;
      for (int j = 0; j < NKB; j++)
        if (!((used >> j) & 1) && scs[j] > best) { best = scs[j]; bi = j; }
      used |= 1u << bi;
      sel[(h * NQB + qi) * 8 + it] = bi;
    }
  }
}

// ---------------- per (h,kblock): lk=softmax(k), KV=lk^T v, slk=sum lk ----
__global__ __launch_bounds__(256) void kv_k(const float* __restrict__ kf,
                                            const float* __restrict__ vf,
                                            float* __restrict__ KV,
                                            float* __restrict__ slk) {
  int h = blockIdx.y, kb = blockIdx.x, t = threadIdx.x;
  __shared__ float lkt[64][128];
  __shared__ float vt[64][128];
  #pragma unroll
  for (int i = 0; i < 8; i++) {
    int idx = i * 256 + t; int r = idx >> 5, d4 = (idx & 31) * 4;
    *(f32x4*)&vt[r][d4] = *(const f32x4*)&vf[(size_t)(kb * 64 + r) * QS + h * DH + d4];
  }
  if (t < 64) {
    const float* kr = kf + (size_t)(kb * 64 + t) * QS + h * DH;
    float m = -3.4e38f;
    for (int d = 0; d < 128; d++) m = fmaxf(m, kr[d]);
    float sum = 0.f;
    for (int d = 0; d < 128; d++) { float e = __expf(kr[d] - m); lkt[t][d] = e; sum += e; }
    float inv = 1.0f / sum;
    for (int d = 0; d < 128; d++) lkt[t][d] *= inv;
  }
  __syncthreads();
  int d1 = t >> 1, hf = t & 1;
  float acc[64];
  #pragma unroll
  for (int i = 0; i < 64; i++) acc[i] = 0.f;
  for (int j = 0; j < 64; j++) {
    float lv = lkt[j][d1];
    #pragma unroll
    for (int dd = 0; dd < 64; dd++) acc[dd] += lv * vt[j][hf * 64 + dd];
  }
  float* out = KV + ((size_t)(h * NKB + kb) * DH + d1) * DH + hf * 64;
  #pragma unroll
  for (int dd = 0; dd < 64; dd++) out[dd] = acc[dd];
  if (t < 128) {
    float a = 0.f;
    for (int j = 0; j < 64; j++) a += lkt[j][t];
    slk[(h * NKB + kb) * DH + t] = a;
  }
}

// ---------------- per head totals ----------------------------------------
__global__ __launch_bounds__(256) void kvtot_k(const float* __restrict__ KV,
                                               const float* __restrict__ slk,
                                               float* __restrict__ KVtot,
                                               float* __restrict__ sltot) {
  int h = blockIdx.y; int e = blockIdx.x * 256 + threadIdx.x;
  float a = 0.f;
  for (int b = 0; b < NKB; b++) a += KV[(size_t)(h * NKB + b) * 16384 + e];
  KVtot[(size_t)h * 16384 + e] = a;
  if (blockIdx.x == 0 && threadIdx.x < 128) {
    float s2 = 0.f;
    for (int b = 0; b < NKB; b++) s2 += slk[(h * NKB + b) * DH + threadIdx.x];
    sltot[h * DH + threadIdx.x] = s2;
  }
}

// ---------------- fused sparse attention + linear fallback ----------------
__global__ __launch_bounds__(256) void attn_k(const float* __restrict__ qf,
                                              const float* __restrict__ kf,
                                              const float* __restrict__ vf,
                                              const int* __restrict__ sel,
                                              const float* __restrict__ KV,
                                              const float* __restrict__ slk,
                                              const float* __restrict__ KVtot,
                                              const float* __restrict__ sltot,
                                              u16* __restrict__ of16) {
  __shared__ u16 qt[128][136];    // q tile bf16 [row][d]  (later: w*lq)
  __shared__ u16 kt[64][136];     // k block bf16 [key][d]
  __shared__ u16 vtT[128][72];    // v block bf16 transposed [d][key]
  __shared__ u16 ptb[128][72];    // P bf16 [row][key]
  __shared__ u16 MT[128][136];    // M^T bf16 [d2][d1]
  __shared__ float mrow[128], lrow[128], dent[128], slsh[128];
  __shared__ int selsh[KSEL];

  int h = blockIdx.y, qi = blockIdx.x, tid = threadIdx.x;
  int w = tid >> 6, lane = tid & 63, quad = lane >> 4, l16 = lane & 15;

  #pragma unroll
  for (int i = 0; i < 16; i++) {
    int idx = i * 256 + tid; int r = idx >> 5, c4 = (idx & 31) * 4;
    f32x4 v = *(const f32x4*)&qf[(size_t)(qi * 128 + r) * QS + h * DH + c4];
    u16x4 pk = { f2bf(v[0]), f2bf(v[1]), f2bf(v[2]), f2bf(v[3]) };
    *(u16x4*)&qt[r][c4] = pk;
  }
  if (tid < KSEL) selsh[tid] = sel[(h * NQB + qi) * 8 + tid];
  __syncthreads();

  float m_run[2][4], l_run[2][4];
  f32x4 zero4 = {0.f, 0.f, 0.f, 0.f};
  f32x4 oacc[2][8];
  #pragma unroll
  for (int mt = 0; mt < 2; mt++) {
    #pragma unroll
    for (int rg = 0; rg < 4; rg++) { m_run[mt][rg] = -3.0e38f; l_run[mt][rg] = 0.f; }
    #pragma unroll
    for (int nt = 0; nt < 8; nt++) oacc[mt][nt] = zero4;
  }

  for (int bi = 0; bi < KSEL; bi++) {
    int b = selsh[bi];
    #pragma unroll
    for (int i = 0; i < 8; i++) {
      int idx = i * 256 + tid; int r = idx >> 5, c4 = (idx & 31) * 4;
      f32x4 v = *(const f32x4*)&kf[(size_t)(b * 64 + r) * QS + h * DH + c4];
      u16x4 pk = { f2bf(v[0]), f2bf(v[1]), f2bf(v[2]), f2bf(v[3]) };
      *(u16x4*)&kt[r][c4] = pk;
    }
    #pragma unroll
    for (int i = 0; i < 16; i++) {
      int idx = i * 256 + tid; int r = idx >> 6, d0 = (idx & 63) * 2;
      f32x2 v = *(const f32x2*)&vf[(size_t)(b * 64 + r) * QS + h * DH + d0];
      vtT[d0][r] = f2bf(v[0]);
      vtT[d0 + 1][r] = f2bf(v[1]);
    }
    __syncthreads();

    f32x4 sacc[2][4];
    #pragma unroll
    for (int mt = 0; mt < 2; mt++)
      #pragma unroll
      for (int nt = 0; nt < 4; nt++) sacc[mt][nt] = zero4;
    #pragma unroll
    for (int kk = 0; kk < 4; kk++) {
      bf16x8 af[2], bfr[4];
      af[0] = __builtin_bit_cast(bf16x8, *(const s16x8*)&qt[w * 32 + l16][kk * 32 + quad * 8]);
      af[1] = __builtin_bit_cast(bf16x8, *(const s16x8*)&qt[w * 32 + 16 + l16][kk * 32 + quad * 8]);
      #pragma unroll
      for (int nt = 0; nt < 4; nt++)
        bfr[nt] = __builtin_bit_cast(bf16x8, *(const s16x8*)&kt[nt * 16 + l16][kk * 32 + quad * 8]);
      #pragma unroll
      for (int mt = 0; mt < 2; mt++)
        #pragma unroll
        for (int nt = 0; nt < 4; nt++)
          sacc[mt][nt] = __builtin_amdgcn_mfma_f32_16x16x32_bf16(af[mt], bfr[nt], sacc[mt][nt], 0, 0, 0);
    }
    const float SCALE = 0.08838834764831845f;
    #pragma unroll
    for (int mt = 0; mt < 2; mt++)
      #pragma unroll
      for (int nt = 0; nt < 4; nt++) sacc[mt][nt] *= SCALE;

    #pragma unroll
    for (int mt = 0; mt < 2; mt++) {
      #pragma unroll
      for (int rg = 0; rg < 4; rg++) {
        float bmax = fmaxf(fmaxf(sacc[mt][0][rg], sacc[mt][1][rg]),
                           fmaxf(sacc[mt][2][rg], sacc[mt][3][rg]));
        bmax = fmaxf(bmax, __shfl_xor(bmax, 1, 64));
        bmax = fmaxf(bmax, __shfl_xor(bmax, 2, 64));
        bmax = fmaxf(bmax, __shfl_xor(bmax, 4, 64));
        bmax = fmaxf(bmax, __shfl_xor(bmax, 8, 64));
        float mold = m_run[mt][rg];
        float mnew = fmaxf(mold, bmax);
        float alpha = __expf(mold - mnew);
        float rs = 0.f;
        #pragma unroll
        for (int nt = 0; nt < 4; nt++) {
          float p = __expf(sacc[mt][nt][rg] - mnew);
          sacc[mt][nt][rg] = p; rs += p;
        }
        rs += __shfl_xor(rs, 1, 64);
        rs += __shfl_xor(rs, 2, 64);
        rs += __shfl_xor(rs, 4, 64);
        rs += __shfl_xor(rs, 8, 64);
        m_run[mt][rg] = mnew;
        l_run[mt][rg] = l_run[mt][rg] * alpha + rs;
        #pragma unroll
        for (int nt = 0; nt < 8; nt++) oacc[mt][nt][rg] *= alpha;
        int r = w * 32 + mt * 16 + quad * 4 + rg;
        #pragma unroll
        for (int nt = 0; nt < 4; nt++) ptb[r][nt * 16 + l16] = f2bf(sacc[mt][nt][rg]);
      }
    }
    __syncthreads();
    #pragma unroll
    for (int kk = 0; kk < 2; kk++) {
      bf16x8 pa[2];
      pa[0] = __builtin_bit_cast(bf16x8, *(const s16x8*)&ptb[w * 32 + l16][kk * 32 + quad * 8]);
      pa[1] = __builtin_bit_cast(bf16x8, *(const s16x8*)&ptb[w * 32 + 16 + l16][kk * 32 + quad * 8]);
      #pragma unroll
      for (int nt = 0; nt < 8; nt++) {
        bf16x8 vb = __builtin_bit_cast(bf16x8, *(const s16x8*)&vtT[nt * 16 + l16][kk * 32 + quad * 8]);
        oacc[0][nt] = __builtin_amdgcn_mfma_f32_16x16x32_bf16(pa[0], vb, oacc[0][nt], 0, 0, 0);
        oacc[1][nt] = __builtin_amdgcn_mfma_f32_16x16x32_bf16(pa[1], vb, oacc[1][nt], 0, 0, 0);
      }
    }
    __syncthreads();
  }

  if (l16 == 0) {
    #pragma unroll
    for (int mt = 0; mt < 2; mt++)
      #pragma unroll
      for (int rg = 0; rg < 4; rg++) {
        int r = w * 32 + mt * 16 + quad * 4 + rg;
        mrow[r] = m_run[mt][rg];
        lrow[r] = l_run[mt][rg];
      }
  }
  if (tid < 128) {
    float a = sltot[h * DH + tid];
    #pragma unroll
    for (int i = 0; i < KSEL; i++) a -= slk[(h * NKB + selsh[i]) * DH + tid];
    slsh[tid] = a;
  }
  // MT = (KVtot - sum_sel KV)^T, vectorized loads (f32x4), transposed stores
  for (int i = 0; i < 16; i++) {
    int idx = i * 256 + tid;
    int e4 = idx * 4;
    int d1 = e4 >> 7, d2 = e4 & 127;
    f32x4 a = *(const f32x4*)&KVtot[(size_t)h * 16384 + e4];
    #pragma unroll
    for (int k2 = 0; k2 < KSEL; k2++) {
      f32x4 s4 = *(const f32x4*)&KV[(size_t)(h * NKB + selsh[k2]) * 16384 + e4];
      a -= s4;
    }
    #pragma unroll
    for (int j = 0; j < 4; j++) MT[d2 + j][d1] = f2bf(a[j]);
  }
  __syncthreads();

  // lq = softmax(q row) * exp(-m): 2 threads per row (64 dims each)
  {
    int r = tid >> 1, hf2 = tid & 1;
    int d0 = hf2 * 64;
    float w_r = __expf(-mrow[r]);
    float mx = -3.4e38f;
    #pragma unroll
    for (int j = 0; j < 64; j++) mx = fmaxf(mx, bf2f(qt[r][d0 + j]));
    mx = fmaxf(mx, __shfl_xor(mx, 1, 64));
    float sum = 0.f;
    #pragma unroll
    for (int j = 0; j < 64; j++) sum += __expf(bf2f(qt[r][d0 + j]) - mx);
    sum += __shfl_xor(sum, 1, 64);
    float sc2 = w_r / sum;
    float dl = 0.f;
    #pragma unroll
    for (int j = 0; j < 64; j++) {
      float lq = __expf(bf2f(qt[r][d0 + j]) - mx) * sc2;
      dl += lq * slsh[d0 + j];
      qt[r][d0 + j] = f2bf(lq);
    }
    dl += __shfl_xor(dl, 1, 64);
    if (hf2 == 0) dent[r] = lrow[r] + dl;
  }
  __syncthreads();

  #pragma unroll
  for (int kk = 0; kk < 4; kk++) {
    bf16x8 af0 = __builtin_bit_cast(bf16x8, *(const s16x8*)&qt[w * 32 + l16][kk * 32 + quad * 8]);
    bf16x8 af1 = __builtin_bit_cast(bf16x8, *(const s16x8*)&qt[w * 32 + 16 + l16][kk * 32 + quad * 8]);
    #pragma unroll
    for (int nt = 0; nt < 8; nt++) {
      bf16x8 mb = __builtin_bit_cast(bf16x8, *(const s16x8*)&MT[nt * 16 + l16][kk * 32 + quad * 8]);
      oacc[0][nt] = __builtin_amdgcn_mfma_f32_16x16x32_bf16(af0, mb, oacc[0][nt], 0, 0, 0);
      oacc[1][nt] = __builtin_amdgcn_mfma_f32_16x16x32_bf16(af1, mb, oacc[1][nt], 0, 0, 0);
    }
  }

  // epilogue: of = oacc / dent, written as f16 (single buffer)
  #pragma unroll
  for (int mt = 0; mt < 2; mt++)
    #pragma unroll
    for (int rg = 0; rg < 4; rg++) {
      int r = w * 32 + mt * 16 + quad * 4 + rg;
      float inv = 1.0f / dent[r];
      #pragma unroll
      for (int nt = 0; nt < 8; nt++) {
        int c = nt * 16 + l16;
        float v = oacc[mt][nt][rg] * inv;
        size_t oi = (size_t)(qi * 128 + r) * DIMM + h * DH + c;
        of16[oi] = __builtin_bit_cast(u16, (_Float16)v);
      }
    }
}

// -------------------------------------------------------------------------
extern "C" void kernel_launch(void* const* d_in, const int* in_sizes, int n_in,
                              void* d_out, int out_size, void* d_ws, size_t ws_size,
                              hipStream_t stream) {
  const float* hs = (const float*)d_in[0];
  const float* fc = (const float*)d_in[1];
  const float* fs = (const float*)d_in[2];
  const float* Wq = (const float*)d_in[3];
  const float* bq = (const float*)d_in[4];
  const float* Wk = (const float*)d_in[5];
  const float* bk = (const float*)d_in[6];
  const float* Wv = (const float*)d_in[7];
  const float* bv = (const float*)d_in[8];
  const float* Wo = (const float*)d_in[9];
  const float* bo = (const float*)d_in[10];
  const float* gq = (const float*)d_in[11];
  const float* gk = (const float*)d_in[12];

  char* p = (char*)d_ws;
  auto alloc = [&](size_t bytes) {
    char* r = p; p += (bytes + 255) & ~(size_t)255; return r;
  };
  u16* WTh = (u16*)alloc((size_t)4 * DIMM * DIMM * 2);
  u16* WTl = (u16*)alloc((size_t)4 * DIMM * DIMM * 2);
  u16* hsh = (u16*)alloc((size_t)SQ * DIMM * 2);   // reused later as of16
  u16* hsl = (u16*)alloc((size_t)SQ * DIMM * 2);
  float* qkv = (float*)alloc((size_t)SQ * QS * 4);
  float* qb = (float*)alloc((size_t)NH * NQB * DH * 4);
  float* kb = (float*)alloc((size_t)NH * NKB * DH * 4);
  int* sel = (int*)alloc((size_t)NH * NQB * 8 * 4);
  float* KV = (float*)alloc((size_t)NH * NKB * DH * DH * 4);
  float* slk = (float*)alloc((size_t)NH * NKB * DH * 4);
  float* KVtot = (float*)alloc((size_t)NH * DH * DH * 4);
  float* sltot = (float*)alloc((size_t)NH * DH * 4);

  float* qf = qkv;
  float* kf = qkv + DIMM;
  float* vf = qkv + 2 * DIMM;

  prep_hs<<<SQ * DIMM / (256 * 8), 256, 0, stream>>>(hs, hsh, hsl);
  prep_w<<<dim3(24, 24, 4), 256, 0, stream>>>(Wq, Wk, Wv, Wo, WTh, WTl);

  gemm3_k<<<dim3(36, 16), 256, 0, stream>>>(hsh, hsl, WTh, WTl, bq, bk, bv, qkv);

  norm_rope_k<<<dim3(SQ, 2), 256, 0, stream>>>(qkv, gq, gk, fc, fs);
  means_k<<<dim3(NQB + NKB, NH), 128, 0, stream>>>(qf, kf, qb, kb);
  topk_k<<<dim3(NQB, NH), 64, 0, stream>>>(qb, kb, sel);
  kv_k<<<dim3(NKB, NH), 256, 0, stream>>>(kf, vf, KV, slk);
  kvtot_k<<<dim3(64, NH), 256, 0, stream>>>(KV, slk, KVtot, sltot);

  // hs staging buffers are dead now; reuse hsh as f16 attention output
  u16* of16 = hsh;
  attn_k<<<dim3(NQB, NH), 256, 0, stream>>>(qf, kf, vf, sel, KV, slk, KVtot, sltot, of16);

  const u16* WTo = WTh + (size_t)3 * DIMM * DIMM;   // f16 W_o^T
  gemm_o<<<dim3(12, 32), 256, 0, stream>>>(of16, WTo, bo, (float*)d_out);
}

// Round 9
// 370.585 us; speedup vs baseline: 1.0910x; 1.0910x over previous
//
#include <hip/hip_runtime.h>
#include <hip/hip_bf16.h>

#define SQ   2048
#define DIMM 1536
#define QS   4608          // fused qkv row stride
#define NH   12
#define DH   128
#define NQB  16
#define NKB  32
#define KSEL 7

typedef unsigned short u16;
typedef __bf16 bf16x8 __attribute__((ext_vector_type(8)));
typedef _Float16 f16x8 __attribute__((ext_vector_type(8)));
typedef short  s16x8  __attribute__((ext_vector_type(8)));
typedef float  f32x4  __attribute__((ext_vector_type(4)));

__device__ __forceinline__ float bf2f(u16 u) {
  unsigned int x = ((unsigned int)u) << 16;
  return __builtin_bit_cast(float, x);
}
__device__ __forceinline__ u16 f2bf(float f) {
  unsigned int x = __builtin_bit_cast(unsigned int, f);
  x += 0x7fffu + ((x >> 16) & 1u);
  return (u16)(x >> 16);
}

typedef __attribute__((address_space(3))) void lds_vt;
typedef const __attribute__((address_space(1))) void g_vt;
__device__ __forceinline__ void dma16(const void* g, void* l) {
  __builtin_amdgcn_global_load_lds((g_vt*)g, (lds_vt*)l, 16, 0, 0);
}

// ---------------- prep: hs f32 -> hi/lo bf16 [r][k] -----------------------
__global__ __launch_bounds__(256) void prep_hs(const float* __restrict__ hs,
                                               u16* __restrict__ hh,
                                               u16* __restrict__ hl) {
  size_t i = ((size_t)blockIdx.x * 256 + threadIdx.x) * 8;
  f32x4 a = *(const f32x4*)&hs[i];
  f32x4 b = *(const f32x4*)&hs[i + 4];
  s16x8 h, l;
  #pragma unroll
  for (int j = 0; j < 4; j++) {
    u16 hj = f2bf(a[j]); h[j] = (short)hj; l[j] = (short)f2bf(a[j] - bf2f(hj));
    u16 hk = f2bf(b[j]); h[4 + j] = (short)hk; l[4 + j] = (short)f2bf(b[j] - bf2f(hk));
  }
  *(s16x8*)&hh[i] = h;
  *(s16x8*)&hl[i] = l;
}

// ---------------- prep: W f32 [k][n] -> WT bf16 hi/lo (wi 0-2) / f16 (wi 3)
__global__ __launch_bounds__(256) void prep_w(const float* __restrict__ W0,
                                              const float* __restrict__ W1,
                                              const float* __restrict__ W2,
                                              const float* __restrict__ W3,
                                              u16* __restrict__ WTh,
                                              u16* __restrict__ WTl) {
  __shared__ float tile[64][65];
  int wi = blockIdx.z;
  const float* W = (wi == 0) ? W0 : (wi == 1) ? W1 : (wi == 2) ? W2 : W3;
  int x = threadIdx.x & 63, y = threadIdx.x >> 6;   // 64 x 4
  int k0 = blockIdx.y * 64, n0 = blockIdx.x * 64;
  #pragma unroll
  for (int i = 0; i < 16; i++) {
    int k = y + i * 4;
    tile[k][x] = W[(size_t)(k0 + k) * DIMM + n0 + x];
  }
  __syncthreads();
  size_t obase = (size_t)wi * DIMM * DIMM;
  #pragma unroll
  for (int i = 0; i < 16; i++) {
    int n = y + i * 4;
    float v = tile[x][n];                 // = W[k0+x][n0+n]
    size_t oi = obase + (size_t)(n0 + n) * DIMM + k0 + x;
    if (wi == 3) {
      WTh[oi] = __builtin_bit_cast(u16, (_Float16)v);   // O-proj: f16 single
    } else {
      u16 h = f2bf(v);
      WTh[oi] = h;
      WTl[oi] = f2bf(v - bf2f(h));
    }
  }
}

// ---------------- fused QKV GEMM (round-7 version: BK=64, swizzled) -------
__global__ __launch_bounds__(256) void gemm3_k(const u16* __restrict__ Ahp,
                                               const u16* __restrict__ Alp,
                                               const u16* __restrict__ WTh,
                                               const u16* __restrict__ WTl,
                                               const float* __restrict__ bq,
                                               const float* __restrict__ bk,
                                               const float* __restrict__ bv,
                                               float* __restrict__ C) {
  __shared__ u16 As[2][128][64];   // [hi/lo][row][k-chunk-swizzled]
  __shared__ u16 Bs[2][128][64];
  const int tid = threadIdx.x;
  const int w = tid >> 6, lane = tid & 63, quad = lane >> 4, l16 = lane & 15;
  const int wr = w >> 1, wc = w & 1;
  const int m_base = blockIdx.y * 128;
  const int nt = blockIdx.x;                 // 0..35
  const int wi = nt / 12;
  const int n_in = (nt % 12) * 128;
  const u16* Bh0 = WTh + ((size_t)wi * DIMM + n_in) * DIMM;
  const u16* Bl0 = WTl + ((size_t)wi * DIMM + n_in) * DIMM;
  const float* bias = (wi == 0) ? bq : (wi == 1) ? bk : bv;
  const bool split = (wi != 2);              // V = single-pass

  const int srow = lane >> 3;                          // 0..7
  const int skc = (((lane & 7) ^ srow) * 8);           // swizzled global col (u16)
  const int rx = (l16 & 7);                            // read-side xor term

  f32x4 zero4 = {0.f, 0.f, 0.f, 0.f};
  f32x4 acc[4][4];
  #pragma unroll
  for (int i = 0; i < 4; i++)
    #pragma unroll
    for (int j = 0; j < 4; j++) acc[i][j] = zero4;

  for (int k0 = 0; k0 < DIMM; k0 += 64) {
    #pragma unroll
    for (int c = 0; c < 4; c++) {
      int r0 = w * 32 + c * 8;
      int row = r0 + srow;
      dma16(&Ahp[(size_t)(m_base + row) * DIMM + k0 + skc], &As[0][r0][0]);
      dma16(&Bh0[(size_t)row * DIMM + k0 + skc], &Bs[0][r0][0]);
      if (split) {
        dma16(&Alp[(size_t)(m_base + row) * DIMM + k0 + skc], &As[1][r0][0]);
        dma16(&Bl0[(size_t)row * DIMM + k0 + skc], &Bs[1][r0][0]);
      }
    }
    __syncthreads();
    #pragma unroll
    for (int kk = 0; kk < 2; kk++) {
      const int coff = ((kk * 4 + quad) ^ rx) * 8;     // swizzled read col (u16)
      bf16x8 afh[4], afl[4], bfh[4], bfl[4];
      #pragma unroll
      for (int i = 0; i < 4; i++)
        afh[i] = __builtin_bit_cast(bf16x8,
                 *(const s16x8*)&As[0][wr * 64 + i * 16 + l16][coff]);
      #pragma unroll
      for (int j = 0; j < 4; j++)
        bfh[j] = __builtin_bit_cast(bf16x8,
                 *(const s16x8*)&Bs[0][wc * 64 + j * 16 + l16][coff]);
      if (split) {
        #pragma unroll
        for (int i = 0; i < 4; i++)
          afl[i] = __builtin_bit_cast(bf16x8,
                   *(const s16x8*)&As[1][wr * 64 + i * 16 + l16][coff]);
        #pragma unroll
        for (int j = 0; j < 4; j++)
          bfl[j] = __builtin_bit_cast(bf16x8,
                   *(const s16x8*)&Bs[1][wc * 64 + j * 16 + l16][coff]);
      }
      #pragma unroll
      for (int i = 0; i < 4; i++)
        #pragma unroll
        for (int j = 0; j < 4; j++) {
          acc[i][j] = __builtin_amdgcn_mfma_f32_16x16x32_bf16(afh[i], bfh[j], acc[i][j], 0, 0, 0);
          if (split) {
            acc[i][j] = __builtin_amdgcn_mfma_f32_16x16x32_bf16(afh[i], bfl[j], acc[i][j], 0, 0, 0);
            acc[i][j] = __builtin_amdgcn_mfma_f32_16x16x32_bf16(afl[i], bfh[j], acc[i][j], 0, 0, 0);
          }
        }
    }
    __syncthreads();
  }
  #pragma unroll
  for (int i = 0; i < 4; i++)
    #pragma unroll
    for (int j = 0; j < 4; j++) {
      int tc = wc * 64 + j * 16 + l16;
      float bv2 = bias[n_in + tc];
      #pragma unroll
      for (int rg = 0; rg < 4; rg++) {
        int r = m_base + wr * 64 + i * 16 + quad * 4 + rg;
        C[(size_t)r * QS + nt * 128 + tc] = acc[i][j][rg] + bv2;
      }
    }
}

// ---------------- O GEMM: single-pass f16, 64x128, BK=64 ------------------
__global__ __launch_bounds__(256) void gemm_o(const u16* __restrict__ Ap,
                                              const u16* __restrict__ Bp,
                                              const float* __restrict__ bias,
                                              float* __restrict__ C) {
  __shared__ u16 As[64][64];
  __shared__ u16 Bs[128][64];
  const int tid = threadIdx.x;
  const int w = tid >> 6, lane = tid & 63, quad = lane >> 4, l16 = lane & 15;
  const int wr = w >> 1, wc = w & 1;
  const int m_base = blockIdx.y * 64, n_base = blockIdx.x * 128;
  const int srow = lane >> 3;
  const int skc = (((lane & 7) ^ srow) * 8);
  const int rx = (l16 & 7);

  f32x4 zero4 = {0.f, 0.f, 0.f, 0.f};
  f32x4 acc[2][4];
  #pragma unroll
  for (int i = 0; i < 2; i++)
    #pragma unroll
    for (int j = 0; j < 4; j++) acc[i][j] = zero4;

  for (int k0 = 0; k0 < DIMM; k0 += 64) {
    #pragma unroll
    for (int c = 0; c < 2; c++) {
      int r0 = w * 16 + c * 8;
      int row = r0 + srow;
      dma16(&Ap[(size_t)(m_base + row) * DIMM + k0 + skc], &As[r0][0]);
    }
    #pragma unroll
    for (int c = 0; c < 4; c++) {
      int r0 = w * 32 + c * 8;
      int row = r0 + srow;
      dma16(&Bp[(size_t)(n_base + row) * DIMM + k0 + skc], &Bs[r0][0]);
    }
    __syncthreads();
    #pragma unroll
    for (int kk = 0; kk < 2; kk++) {
      const int coff = ((kk * 4 + quad) ^ rx) * 8;
      f16x8 af[2], bf[4];
      #pragma unroll
      for (int i = 0; i < 2; i++)
        af[i] = __builtin_bit_cast(f16x8,
                *(const s16x8*)&As[wr * 32 + i * 16 + l16][coff]);
      #pragma unroll
      for (int j = 0; j < 4; j++)
        bf[j] = __builtin_bit_cast(f16x8,
                *(const s16x8*)&Bs[wc * 64 + j * 16 + l16][coff]);
      #pragma unroll
      for (int i = 0; i < 2; i++)
        #pragma unroll
        for (int j = 0; j < 4; j++)
          acc[i][j] = __builtin_amdgcn_mfma_f32_16x16x32_f16(af[i], bf[j], acc[i][j], 0, 0, 0);
    }
    __syncthreads();
  }
  #pragma unroll
  for (int i = 0; i < 2; i++)
    #pragma unroll
    for (int j = 0; j < 4; j++) {
      int c = n_base + wc * 64 + j * 16 + l16;
      float bv2 = bias[c];
      #pragma unroll
      for (int rg = 0; rg < 4; rg++) {
        int r = m_base + wr * 32 + i * 16 + quad * 4 + rg;
        C[(size_t)r * DIMM + c] = acc[i][j][rg] + bv2;
      }
    }
}

// ---------------- RMSNorm + RoPE (on fused qkv buffer) --------------------
__global__ __launch_bounds__(256) void norm_rope_k(float* __restrict__ qkv,
                                                   const float* __restrict__ gq,
                                                   const float* __restrict__ gk,
                                                   const float* __restrict__ fc,
                                                   const float* __restrict__ fs) {
  int s = blockIdx.x;
  float* row = qkv + (size_t)s * QS + (blockIdx.y == 0 ? 0 : DIMM);
  const float* g = (blockIdx.y == 0) ? gq : gk;
  int t = threadIdx.x;
  float ss = 0.f;
  #pragma unroll
  for (int i = 0; i < 6; i++) {
    float v = row[t + i * 256];
    ss += v * v;
  }
  #pragma unroll
  for (int m = 1; m < 64; m <<= 1) ss += __shfl_xor(ss, m, 64);
  __shared__ float wsum[4];
  if ((t & 63) == 0) wsum[t >> 6] = ss;
  __syncthreads();
  float tot = wsum[0] + wsum[1] + wsum[2] + wsum[3];
  float sc = rsqrtf(tot / 1536.0f + 1e-6f);
  #pragma unroll
  for (int i = 0; i < 3; i++) {
    int p = t + i * 256;
    int h = p >> 6, ip = p & 63;
    int base = h * 128 + 2 * ip;
    float x1 = row[base] * sc * g[base];
    float x2 = row[base + 1] * sc * g[base + 1];
    float c = fc[(size_t)s * 128 + 2 * ip];
    float sn = fs[(size_t)s * 128 + 2 * ip + 1];
    row[base]     = x1 * c - x2 * sn;
    row[base + 1] = x1 * sn + x2 * c;
  }
}

// ---------------- prep q/k -> bf16, h-major, XOR-pre-swizzled rows --------
// out[h][s][c*8+e] = f2bf(qkv[s][off + h*128 + g*8+e]),  g = (c&8)|((c^(s&7))&7)
__global__ __launch_bounds__(256) void prep_qk(const float* __restrict__ qkv,
                                               u16* __restrict__ qbf,
                                               u16* __restrict__ kbf) {
  int s0 = blockIdx.x * 128, h = blockIdx.y, z = blockIdx.z;
  int off = z * DIMM;
  u16* out = (z ? kbf : qbf) + ((size_t)h * SQ + s0) * 128;
  int tid = threadIdx.x;
  #pragma unroll
  for (int i = 0; i < 8; i++) {
    int idx = i * 256 + tid;            // 128 rows x 16 chunks
    int r = idx >> 4, c = idx & 15;
    int g = (c & 8) | ((c ^ (r & 7)) & 7);
    const float* src = qkv + (size_t)(s0 + r) * QS + off + h * DH + g * 8;
    f32x4 a = *(const f32x4*)src;
    f32x4 b = *(const f32x4*)(src + 4);
    s16x8 o;
    #pragma unroll
    for (int e = 0; e < 4; e++) { o[e] = (short)f2bf(a[e]); o[4 + e] = (short)f2bf(b[e]); }
    *(s16x8*)&out[r * 128 + c * 8] = o;
  }
}

// ---------------- prep v -> bf16 transposed [h][b][d][key], swizzled ------
// out[h][b][d][c*8+e] = f2bf(v[b*64 + (c^(d&7))*8+e][h*128+d])
__global__ __launch_bounds__(256) void prep_vT(const float* __restrict__ vf,
                                               u16* __restrict__ vbfT) {
  __shared__ float vt[64][132];
  int b = blockIdx.x, h = blockIdx.y, tid = threadIdx.x;
  #pragma unroll
  for (int i = 0; i < 8; i++) {
    int idx = i * 256 + tid; int key = idx >> 5, d4 = (idx & 31) * 4;
    *(f32x4*)&vt[key][d4] = *(const f32x4*)&vf[(size_t)(b * 64 + key) * QS + h * DH + d4];
  }
  __syncthreads();
  u16* out = vbfT + ((size_t)(h * NKB + b)) * 128 * 64;
  #pragma unroll
  for (int i = 0; i < 4; i++) {
    int idx = i * 256 + tid;            // 128 rows(d) x 8 chunks
    int d = idx >> 3, c = idx & 7;
    int g = c ^ (d & 7);
    s16x8 o;
    #pragma unroll
    for (int e = 0; e < 8; e++) o[e] = (short)f2bf(vt[g * 8 + e][d]);
    *(s16x8*)&out[d * 64 + c * 8] = o;
  }
}

// ---------------- block means -------------------------------------------
__global__ __launch_bounds__(128) void means_k(const float* __restrict__ qf,
                                               const float* __restrict__ kf,
                                               float* __restrict__ qb,
                                               float* __restrict__ kb) {
  int h = blockIdx.y, t = threadIdx.x;
  if (blockIdx.x < NQB) {
    int qi = blockIdx.x;
    float a = 0.f;
    for (int r = 0; r < 128; r++) a += qf[(size_t)(qi * 128 + r) * QS + h * DH + t];
    qb[(h * NQB + qi) * DH + t] = a * (1.0f / 128.0f);
  } else {
    int ki = blockIdx.x - NQB;
    float a = 0.f;
    for (int r = 0; r < 64; r++) a += kf[(size_t)(ki * 64 + r) * QS + h * DH + t];
    kb[(h * NKB + ki) * DH + t] = a * (1.0f / 64.0f);
  }
}

// ---------------- block scores + top-7 selection -------------------------
__global__ __launch_bounds__(64) void topk_k(const float* __restrict__ qb,
                                             const float* __restrict__ kb,
                                             int* __restrict__ sel) {
  int h = blockIdx.y, qi = blockIdx.x, t = threadIdx.x;
  __shared__ float scs[NKB];
  if (t < NKB) {
    float a = 0.f;
    for (int d = 0; d < DH; d++)
      a += qb[(h * NQB + qi) * DH + d] * kb[(h * NKB + t) * DH + d];
    scs[t] = a;
  }
  __syncthreads();
  if (t == 0) {
    unsigned int used = 0;
    for (int it = 0; it < KSEL; it++) {
      float best = -3.4e38f; int bi = 0;
      for (int j = 0; j < NKB; j++)
        if (!((used >> j) & 1) && scs[j] > best) { best = scs[j]; bi = j; }
      used |= 1u << bi;
      sel[(h * NQB + qi) * 8 + it] = bi;
    }
  }
}

// ---------------- per (h,kblock): lk=softmax(k), KV=lk^T v, slk=sum lk ----
__global__ __launch_bounds__(256) void kv_k(const float* __restrict__ kf,
                                            const float* __restrict__ vf,
                                            float* __restrict__ KV,
                                            float* __restrict__ slk) {
  int h = blockIdx.y, kb = blockIdx.x, t = threadIdx.x;
  __shared__ float lkt[64][128];
  __shared__ float vt[64][128];
  #pragma unroll
  for (int i = 0; i < 8; i++) {
    int idx = i * 256 + t; int r = idx >> 5, d4 = (idx & 31) * 4;
    *(f32x4*)&vt[r][d4] = *(const f32x4*)&vf[(size_t)(kb * 64 + r) * QS + h * DH + d4];
  }
  if (t < 64) {
    const float* kr = kf + (size_t)(kb * 64 + t) * QS + h * DH;
    float m = -3.4e38f;
    for (int d = 0; d < 128; d++) m = fmaxf(m, kr[d]);
    float sum = 0.f;
    for (int d = 0; d < 128; d++) { float e = __expf(kr[d] - m); lkt[t][d] = e; sum += e; }
    float inv = 1.0f / sum;
    for (int d = 0; d < 128; d++) lkt[t][d] *= inv;
  }
  __syncthreads();
  int d1 = t >> 1, hf = t & 1;
  float acc[64];
  #pragma unroll
  for (int i = 0; i < 64; i++) acc[i] = 0.f;
  for (int j = 0; j < 64; j++) {
    float lv = lkt[j][d1];
    #pragma unroll
    for (int dd = 0; dd < 64; dd++) acc[dd] += lv * vt[j][hf * 64 + dd];
  }
  float* out = KV + ((size_t)(h * NKB + kb) * DH + d1) * DH + hf * 64;
  #pragma unroll
  for (int dd = 0; dd < 64; dd++) out[dd] = acc[dd];
  if (t < 128) {
    float a = 0.f;
    for (int j = 0; j < 64; j++) a += lkt[j][t];
    slk[(h * NKB + kb) * DH + t] = a;
  }
}

// ---------------- per head totals ----------------------------------------
__global__ __launch_bounds__(256) void kvtot_k(const float* __restrict__ KV,
                                               const float* __restrict__ slk,
                                               float* __restrict__ KVtot,
                                               float* __restrict__ sltot) {
  int h = blockIdx.y; int e = blockIdx.x * 256 + threadIdx.x;
  float a = 0.f;
  for (int b = 0; b < NKB; b++) a += KV[(size_t)(h * NKB + b) * 16384 + e];
  KVtot[(size_t)h * 16384 + e] = a;
  if (blockIdx.x == 0 && threadIdx.x < 128) {
    float s2 = 0.f;
    for (int b = 0; b < NKB; b++) s2 += slk[(h * NKB + b) * DH + threadIdx.x];
    sltot[h * DH + threadIdx.x] = s2;
  }
}

// ---------------- fused sparse attention + linear fallback ----------------
// q/k/v staged from pre-packed swizzled bf16 buffers via global_load_lds.
__global__ __launch_bounds__(256) void attn_k(const u16* __restrict__ qbf,
                                              const u16* __restrict__ kbf,
                                              const u16* __restrict__ vbfT,
                                              const int* __restrict__ sel,
                                              const float* __restrict__ KV,
                                              const float* __restrict__ slk,
                                              const float* __restrict__ KVtot,
                                              const float* __restrict__ sltot,
                                              u16* __restrict__ of16) {
  __shared__ u16 qt[128 * 128];   // swizzled rows (16 chunks, xor r&7)
  __shared__ u16 kt[64 * 128];    // swizzled rows
  __shared__ u16 vtT[128 * 64];   // [d][key] swizzled (8 chunks, xor d&7)
  __shared__ u16 ptb[128][72];    // P bf16 [row][key] (padded, plain)
  __shared__ u16 MT[128][136];    // M^T bf16 (plain)
  __shared__ float mrow[128], lrow[128], dent[128], slsh[128];
  __shared__ int selsh[KSEL];

  int h = blockIdx.y, qi = blockIdx.x, tid = threadIdx.x;
  int w = tid >> 6, lane = tid & 63, quad = lane >> 4, l16 = lane & 15;

  // qt: 32 KB straight DMA (pre-swizzled in gmem)
  {
    const u16* qsrc = qbf + ((size_t)h * SQ + qi * 128) * 128;
    #pragma unroll
    for (int c = 0; c < 8; c++)
      dma16(qsrc + (w * 32 + c * 4) * 128 + lane * 8, &qt[(w * 32 + c * 4) * 128]);
  }
  if (tid < KSEL) selsh[tid] = sel[(h * NQB + qi) * 8 + tid];
  __syncthreads();

  float m_run[2][4], l_run[2][4];
  f32x4 zero4 = {0.f, 0.f, 0.f, 0.f};
  f32x4 oacc[2][8];
  #pragma unroll
  for (int mt = 0; mt < 2; mt++) {
    #pragma unroll
    for (int rg = 0; rg < 4; rg++) { m_run[mt][rg] = -3.0e38f; l_run[mt][rg] = 0.f; }
    #pragma unroll
    for (int nt = 0; nt < 8; nt++) oacc[mt][nt] = zero4;
  }

  for (int bi = 0; bi < KSEL; bi++) {
    int b = selsh[bi];
    {
      const u16* ksrc = kbf + ((size_t)h * SQ + b * 64) * 128;
      #pragma unroll
      for (int c = 0; c < 4; c++)
        dma16(ksrc + (w * 16 + c * 4) * 128 + lane * 8, &kt[(w * 16 + c * 4) * 128]);
      const u16* vsrc = vbfT + ((size_t)(h * NKB + b)) * 128 * 64;
      #pragma unroll
      for (int c = 0; c < 4; c++)
        dma16(vsrc + (w * 32 + c * 8) * 64 + lane * 8, &vtT[(w * 32 + c * 8) * 64]);
    }
    __syncthreads();

    f32x4 sacc[2][4];
    #pragma unroll
    for (int mt = 0; mt < 2; mt++)
      #pragma unroll
      for (int nt = 0; nt < 4; nt++) sacc[mt][nt] = zero4;
    #pragma unroll
    for (int kk = 0; kk < 4; kk++) {
      const int kkq = kk * 4 + quad;
      const int qoff = ((kkq & 8) | ((kkq ^ (l16 & 7)) & 7)) * 8;
      bf16x8 af[2], bfr[4];
      af[0] = __builtin_bit_cast(bf16x8, *(const s16x8*)&qt[(w * 32 + l16) * 128 + qoff]);
      af[1] = __builtin_bit_cast(bf16x8, *(const s16x8*)&qt[(w * 32 + 16 + l16) * 128 + qoff]);
      #pragma unroll
      for (int nt = 0; nt < 4; nt++)
        bfr[nt] = __builtin_bit_cast(bf16x8, *(const s16x8*)&kt[(nt * 16 + l16) * 128 + qoff]);
      #pragma unroll
      for (int mt = 0; mt < 2; mt++)
        #pragma unroll
        for (int nt = 0; nt < 4; nt++)
          sacc[mt][nt] = __builtin_amdgcn_mfma_f32_16x16x32_bf16(af[mt], bfr[nt], sacc[mt][nt], 0, 0, 0);
    }
    const float SCALE = 0.08838834764831845f;
    #pragma unroll
    for (int mt = 0; mt < 2; mt++)
      #pragma unroll
      for (int nt = 0; nt < 4; nt++) sacc[mt][nt] *= SCALE;

    #pragma unroll
    for (int mt = 0; mt < 2; mt++) {
      #pragma unroll
      for (int rg = 0; rg < 4; rg++) {
        float bmax = fmaxf(fmaxf(sacc[mt][0][rg], sacc[mt][1][rg]),
                           fmaxf(sacc[mt][2][rg], sacc[mt][3][rg]));
        bmax = fmaxf(bmax, __shfl_xor(bmax, 1, 64));
        bmax = fmaxf(bmax, __shfl_xor(bmax, 2, 64));
        bmax = fmaxf(bmax, __shfl_xor(bmax, 4, 64));
        bmax = fmaxf(bmax, __shfl_xor(bmax, 8, 64));
        float mold = m_run[mt][rg];
        float mnew = fmaxf(mold, bmax);
        float alpha = __expf(mold - mnew);
        float rs = 0.f;
        #pragma unroll
        for (int nt = 0; nt < 4; nt++) {
          float p = __expf(sacc[mt][nt][rg] - mnew);
          sacc[mt][nt][rg] = p; rs += p;
        }
        rs += __shfl_xor(rs, 1, 64);
        rs += __shfl_xor(rs, 2, 64);
        rs += __shfl_xor(rs, 4, 64);
        rs += __shfl_xor(rs, 8, 64);
        m_run[mt][rg] = mnew;
        l_run[mt][rg] = l_run[mt][rg] * alpha + rs;
        #pragma unroll
        for (int nt = 0; nt < 8; nt++) oacc[mt][nt][rg] *= alpha;
        int r = w * 32 + mt * 16 + quad * 4 + rg;
        #pragma unroll
        for (int nt = 0; nt < 4; nt++) ptb[r][nt * 16 + l16] = f2bf(sacc[mt][nt][rg]);
      }
    }
    __syncthreads();
    #pragma unroll
    for (int kk = 0; kk < 2; kk++) {
      bf16x8 pa[2];
      pa[0] = __builtin_bit_cast(bf16x8, *(const s16x8*)&ptb[w * 32 + l16][kk * 32 + quad * 8]);
      pa[1] = __builtin_bit_cast(bf16x8, *(const s16x8*)&ptb[w * 32 + 16 + l16][kk * 32 + quad * 8]);
      #pragma unroll
      for (int nt = 0; nt < 8; nt++) {
        const int voff = ((kk * 4 + quad) ^ (l16 & 7)) * 8;
        bf16x8 vb = __builtin_bit_cast(bf16x8, *(const s16x8*)&vtT[(nt * 16 + l16) * 64 + voff]);
        oacc[0][nt] = __builtin_amdgcn_mfma_f32_16x16x32_bf16(pa[0], vb, oacc[0][nt], 0, 0, 0);
        oacc[1][nt] = __builtin_amdgcn_mfma_f32_16x16x32_bf16(pa[1], vb, oacc[1][nt], 0, 0, 0);
      }
    }
    __syncthreads();
  }

  if (l16 == 0) {
    #pragma unroll
    for (int mt = 0; mt < 2; mt++)
      #pragma unroll
      for (int rg = 0; rg < 4; rg++) {
        int r = w * 32 + mt * 16 + quad * 4 + rg;
        mrow[r] = m_run[mt][rg];
        lrow[r] = l_run[mt][rg];
      }
  }
  if (tid < 128) {
    float a = sltot[h * DH + tid];
    #pragma unroll
    for (int i = 0; i < KSEL; i++) a -= slk[(h * NKB + selsh[i]) * DH + tid];
    slsh[tid] = a;
  }
  // MT = (KVtot - sum_sel KV)^T
  for (int i = 0; i < 16; i++) {
    int idx = i * 256 + tid;
    int e4 = idx * 4;
    int d1 = e4 >> 7, d2 = e4 & 127;
    f32x4 a = *(const f32x4*)&KVtot[(size_t)h * 16384 + e4];
    #pragma unroll
    for (int k2 = 0; k2 < KSEL; k2++) {
      f32x4 s4 = *(const f32x4*)&KV[(size_t)(h * NKB + selsh[k2]) * 16384 + e4];
      a -= s4;
    }
    #pragma unroll
    for (int j = 0; j < 4; j++) MT[d2 + j][d1] = f2bf(a[j]);
  }
  __syncthreads();

  // lq = softmax(q row) * exp(-m): 2 threads per row, swizzle-aware qt access
  {
    int r = tid >> 1, hf2 = tid & 1;
    float w_r = __expf(-mrow[r]);
    float mx = -3.4e38f;
    #pragma unroll
    for (int g = 0; g < 8; g++) {
      int gc = hf2 * 8 + g;
      int c = (gc & 8) | ((gc ^ (r & 7)) & 7);
      #pragma unroll
      for (int e = 0; e < 8; e++) mx = fmaxf(mx, bf2f(qt[r * 128 + c * 8 + e]));
    }
    mx = fmaxf(mx, __shfl_xor(mx, 1, 64));
    float sum = 0.f;
    #pragma unroll
    for (int g = 0; g < 8; g++) {
      int gc = hf2 * 8 + g;
      int c = (gc & 8) | ((gc ^ (r & 7)) & 7);
      #pragma unroll
      for (int e = 0; e < 8; e++) sum += __expf(bf2f(qt[r * 128 + c * 8 + e]) - mx);
    }
    sum += __shfl_xor(sum, 1, 64);
    float sc2 = w_r / sum;
    float dl = 0.f;
    #pragma unroll
    for (int g = 0; g < 8; g++) {
      int gc = hf2 * 8 + g;
      int c = (gc & 8) | ((gc ^ (r & 7)) & 7);
      #pragma unroll
      for (int e = 0; e < 8; e++) {
        float lq = __expf(bf2f(qt[r * 128 + c * 8 + e]) - mx) * sc2;
        dl += lq * slsh[gc * 8 + e];
        qt[r * 128 + c * 8 + e] = f2bf(lq);
      }
    }
    dl += __shfl_xor(dl, 1, 64);
    if (hf2 == 0) dent[r] = lrow[r] + dl;
  }
  __syncthreads();

  #pragma unroll
  for (int kk = 0; kk < 4; kk++) {
    const int kkq = kk * 4 + quad;
    const int qoff = ((kkq & 8) | ((kkq ^ (l16 & 7)) & 7)) * 8;
    bf16x8 af0 = __builtin_bit_cast(bf16x8, *(const s16x8*)&qt[(w * 32 + l16) * 128 + qoff]);
    bf16x8 af1 = __builtin_bit_cast(bf16x8, *(const s16x8*)&qt[(w * 32 + 16 + l16) * 128 + qoff]);
    #pragma unroll
    for (int nt = 0; nt < 8; nt++) {
      bf16x8 mb = __builtin_bit_cast(bf16x8, *(const s16x8*)&MT[nt * 16 + l16][kk * 32 + quad * 8]);
      oacc[0][nt] = __builtin_amdgcn_mfma_f32_16x16x32_bf16(af0, mb, oacc[0][nt], 0, 0, 0);
      oacc[1][nt] = __builtin_amdgcn_mfma_f32_16x16x32_bf16(af1, mb, oacc[1][nt], 0, 0, 0);
    }
  }

  // epilogue: of = oacc / dent, f16
  #pragma unroll
  for (int mt = 0; mt < 2; mt++)
    #pragma unroll
    for (int rg = 0; rg < 4; rg++) {
      int r = w * 32 + mt * 16 + quad * 4 + rg;
      float inv = 1.0f / dent[r];
      #pragma unroll
      for (int nt = 0; nt < 8; nt++) {
        int c = nt * 16 + l16;
        float v = oacc[mt][nt][rg] * inv;
        size_t oi = (size_t)(qi * 128 + r) * DIMM + h * DH + c;
        of16[oi] = __builtin_bit_cast(u16, (_Float16)v);
      }
    }
}

// -------------------------------------------------------------------------
extern "C" void kernel_launch(void* const* d_in, const int* in_sizes, int n_in,
                              void* d_out, int out_size, void* d_ws, size_t ws_size,
                              hipStream_t stream) {
  const float* hs = (const float*)d_in[0];
  const float* fc = (const float*)d_in[1];
  const float* fs = (const float*)d_in[2];
  const float* Wq = (const float*)d_in[3];
  const float* bq = (const float*)d_in[4];
  const float* Wk = (const float*)d_in[5];
  const float* bk = (const float*)d_in[6];
  const float* Wv = (const float*)d_in[7];
  const float* bv = (const float*)d_in[8];
  const float* Wo = (const float*)d_in[9];
  const float* bo = (const float*)d_in[10];
  const float* gq = (const float*)d_in[11];
  const float* gk = (const float*)d_in[12];

  char* p = (char*)d_ws;
  auto alloc = [&](size_t bytes) {
    char* r = p; p += (bytes + 255) & ~(size_t)255; return r;
  };
  u16* WTh = (u16*)alloc((size_t)4 * DIMM * DIMM * 2);
  u16* WTl = (u16*)alloc((size_t)4 * DIMM * DIMM * 2);
  u16* hsh = (u16*)alloc((size_t)SQ * DIMM * 2);   // reused later as of16
  u16* hsl = (u16*)alloc((size_t)SQ * DIMM * 2);
  float* qkv = (float*)alloc((size_t)SQ * QS * 4);
  u16* qbf = (u16*)alloc((size_t)NH * SQ * DH * 2);
  u16* kbf = (u16*)alloc((size_t)NH * SQ * DH * 2);
  u16* vbfT = (u16*)alloc((size_t)NH * NKB * DH * 64 * 2);
  float* qb = (float*)alloc((size_t)NH * NQB * DH * 4);
  float* kb = (float*)alloc((size_t)NH * NKB * DH * 4);
  int* sel = (int*)alloc((size_t)NH * NQB * 8 * 4);
  float* KV = (float*)alloc((size_t)NH * NKB * DH * DH * 4);
  float* slk = (float*)alloc((size_t)NH * NKB * DH * 4);
  float* KVtot = (float*)alloc((size_t)NH * DH * DH * 4);
  float* sltot = (float*)alloc((size_t)NH * DH * 4);

  float* qf = qkv;
  float* kf = qkv + DIMM;
  float* vf = qkv + 2 * DIMM;

  prep_hs<<<SQ * DIMM / (256 * 8), 256, 0, stream>>>(hs, hsh, hsl);
  prep_w<<<dim3(24, 24, 4), 256, 0, stream>>>(Wq, Wk, Wv, Wo, WTh, WTl);

  gemm3_k<<<dim3(36, 16), 256, 0, stream>>>(hsh, hsl, WTh, WTl, bq, bk, bv, qkv);

  norm_rope_k<<<dim3(SQ, 2), 256, 0, stream>>>(qkv, gq, gk, fc, fs);
  means_k<<<dim3(NQB + NKB, NH), 128, 0, stream>>>(qf, kf, qb, kb);
  topk_k<<<dim3(NQB, NH), 64, 0, stream>>>(qb, kb, sel);
  kv_k<<<dim3(NKB, NH), 256, 0, stream>>>(kf, vf, KV, slk);
  kvtot_k<<<dim3(64, NH), 256, 0, stream>>>(KV, slk, KVtot, sltot);
  prep_qk<<<dim3(16, NH, 2), 256, 0, stream>>>(qkv, qbf, kbf);
  prep_vT<<<dim3(NKB, NH), 256, 0, stream>>>(vf, vbfT);

  // hs staging buffers are dead now; reuse hsh as f16 attention output
  u16* of16 = hsh;
  attn_k<<<dim3(NQB, NH), 256, 0, stream>>>(qbf, kbf, vbfT, sel, KV, slk, KVtot, sltot, of16);

  const u16* WTo = WTh + (size_t)3 * DIMM * DIMM;   // f16 W_o^T
  gemm_o<<<dim3(12, 32), 256, 0, stream>>>(of16, WTo, bo, (float*)d_out);
}